// Round 1
// baseline (4264.495 us; speedup 1.0000x reference)
//
#include <hip/hip_runtime.h>

// Problem constants: T=128, B=128, S=128, H=1024, E=512, V=32000, L=2
#define TT 128
#define BB 128
#define SS 128
#define HH 1024
#define EE 512
#define BH (BB*HH)   // 131072

typedef unsigned short u16;                                   // bf16 bits
typedef __attribute__((ext_vector_type(8))) short s8v;        // MFMA A/B fragment (8 bf16)
typedef __attribute__((ext_vector_type(4))) float f32x4;      // MFMA C/D fragment

__device__ __forceinline__ float b2f(u16 u) {
    union { unsigned int i; float f; } v; v.i = ((unsigned int)u) << 16; return v.f;
}
__device__ __forceinline__ u16 f2b(float f) {
    union { float f; unsigned int i; } v; v.f = f;
    unsigned int x = v.i;
    x = x + 0x7fffu + ((x >> 16) & 1u);   // round-to-nearest-even
    return (u16)(x >> 16);
}
__device__ __forceinline__ float sigm(float x) {
    float t = __expf(-fabsf(x));
    float p = 1.0f / (1.0f + t);
    return x >= 0.0f ? p : 1.0f - p;
}
__device__ __forceinline__ float tanh_(float x) {
    float t = __expf(-2.0f * fabsf(x));
    float r = (1.0f - t) / (1.0f + t);
    return x >= 0.0f ? r : -r;
}

#define MFMA(a, b, c) __builtin_amdgcn_mfma_f32_16x16x32_bf16((a), (b), (c), 0, 0, 0)

// ---------------------------------------------------------------------------
// fp32 -> bf16 bulk convert (n multiple of 4)
// ---------------------------------------------------------------------------
__global__ __launch_bounds__(256)
void cvt_k(const float* __restrict__ s, u16* __restrict__ d, int n)
{
    const int i = (blockIdx.x * 256 + threadIdx.x) * 4;
    if (i < n) {
        const float4 v = *(const float4*)(s + i);
        ushort4 o;
        o.x = f2b(v.x); o.y = f2b(v.y); o.z = f2b(v.z); o.w = f2b(v.w);
        *(ushort4*)(d + i) = o;
    }
}

// ---------------------------------------------------------------------------
// Embedding gather + cast: X[t*B+b, :] = bf16(emb[toks[t,b], :])
// ---------------------------------------------------------------------------
__global__ __launch_bounds__(128)
void gather_k(const int* __restrict__ toks, const float* __restrict__ emb,
              u16* __restrict__ X)
{
    const int row = blockIdx.x;
    const int tok = toks[row];
    const int c = threadIdx.x * 4;
    const float4 v = *(const float4*)(emb + (size_t)tok * EE + c);
    ushort4 o;
    o.x = f2b(v.x); o.y = f2b(v.y); o.z = f2b(v.z); o.w = f2b(v.w);
    *(ushort4*)(X + (size_t)row * EE + c) = o;
}

// ---------------------------------------------------------------------------
// init: h0ring slot0 <- bf16(h0 layer0); h1init <- bf16(h0 layer1); barcnt=0
// ---------------------------------------------------------------------------
__global__ __launch_bounds__(256)
void init_k(const float* __restrict__ h0in,
            u16* __restrict__ h0ring, u16* __restrict__ h1init,
            int* __restrict__ barcnt)
{
    const int i = blockIdx.x * 256 + threadIdx.x;   // [0, 2*BH)
    const u16 hb = f2b(h0in[i]);
    if (i < BH) h0ring[i] = hb;
    else        h1init[i - BH] = hb;
    if (i == 0) *barcnt = 0;
}

// ---------------------------------------------------------------------------
// Persistent fused 2-layer LSTM scan. 256 blocks (1/CU) x 512 threads.
// Weights LDS-resident. h-state flows through WRITE-ONCE ring buffers
// (h0ring[129 slots], H1all doubles as the h1 ring), so readers use plain
// cached loads with NO cache invalidation: a ring address was never cached
// locally, so the load misses L1/L2 and fetches from LLC, which is fresh
// because each writer's RELEASE atomic-add drained vmcnt and wrote back its
// XCD L2 first. Within an XCD the 32 blocks then share the line via L2.
// Column swizzle: same-XCD blocks (assuming bk%8 XCD round-robin — perf
// heuristic only) own contiguous columns so h-writes form whole 128B lines.
//
// R1 change: (1) post-barrier h0/h1 GEMMs fused into one loop — 2 A-miss
// streams interleaved, 16 outstanding 16B loads/lane instead of 8, 3 MFMAs
// per iter; (2) separate gst0/gst1 LDS staging buffers so the two pointwise
// phases share ONE barrier pair (4 -> 2 __syncthreads per phase).
// ---------------------------------------------------------------------------
__global__ __launch_bounds__(512, 1)
void scan_k(const float* __restrict__ Wih0, const float* __restrict__ Whh0,
            const float* __restrict__ Wih1, const float* __restrict__ Whh1,
            const float* __restrict__ bih0, const float* __restrict__ bhh0,
            const float* __restrict__ bih1, const float* __restrict__ bhh1,
            const float* __restrict__ c0in,
            const u16* __restrict__ Xb,
            u16* __restrict__ h0ring,   // 129 slots of BH (slot 0 = init)
            const u16* __restrict__ h1init,
            u16* __restrict__ H1all,    // T * BH (= h1 ring, slot t = step t)
            float* __restrict__ outT,   // d_out + T*BH: [hT (2BH), cT (2BH)]
            int* __restrict__ barcnt)
{
    extern __shared__ u16 lds[];
    u16* W0x = lds;                     // 16*4*16*8  =  8192 u16 (16 KB)
    u16* W0h = W0x + 16*4*16*8;         // 32*4*16*8  = 16384 u16 (32 KB)
    u16* W1x = W0h + 32*4*16*8;         //            = 16384 u16 (32 KB)
    u16* W1h = W1x + 32*4*16*8;         //            = 16384 u16 (32 KB)
    float* gst0 = (float*)(W1h + 32*4*16*8);  // 8*16*20 = 2560 fp32 (10 KB)
    float* gst1 = gst0 + 8*16*20;             // 8*16*20 = 2560 fp32 (10 KB)

    const int tid  = threadIdx.x;
    const int bk   = blockIdx.x;
    // swizzle: XCD (bk&7) owns contiguous 128-col span
    const int j0   = (((bk & 7) << 5) | (bk >> 3)) * 4;
    const int lane = tid & 63;
    const int w    = tid >> 6;          // wave 0..7  (m-tile = w)
    const int l15  = lane & 15, quad = lane >> 4;

    // ---- one-time: weights -> LDS (fp32 -> bf16, swizzled) ----
    auto loadW = [&](const float* src, int K, u16* dst) {
        const int ntup = (K / 32) * 4 * 16;
        for (int idx = tid; idx < ntup; idx += 512) {
            const int n = idx & 15, q = (idx >> 4) & 3, kc = idx >> 6;
            const int col = ((n >> 2) * HH) + j0 + (n & 3);   // gate*H + j
            const float* sp = src + (size_t)col * K + kc * 32 + q * 8;
            const float4 v0 = *(const float4*)(sp);
            const float4 v1 = *(const float4*)(sp + 4);
            u16* dp = dst + (size_t)idx * 8;
            dp[0] = f2b(v0.x); dp[1] = f2b(v0.y); dp[2] = f2b(v0.z); dp[3] = f2b(v0.w);
            dp[4] = f2b(v1.x); dp[5] = f2b(v1.y); dp[6] = f2b(v1.z); dp[7] = f2b(v1.w);
        }
    };
    loadW(Wih0, EE, W0x);
    loadW(Whh0, HH, W0h);
    loadW(Wih1, HH, W1x);
    loadW(Whh1, HH, W1h);

    // pointwise thread mapping: tid -> (row, output col)
    const int prow = tid >> 2;          // 0..127
    const int pjj  = tid & 3;
    const int pj   = j0 + pjj;
    const int pw   = prow >> 4, pr16 = prow & 15;

    float c0 = c0in[(size_t)0 * BH + (size_t)prow * HH + pj];
    float c1 = c0in[(size_t)1 * BH + (size_t)prow * HH + pj];
    float b0[4], b1[4];
    #pragma unroll
    for (int g = 0; g < 4; ++g) {
        b0[g] = bih0[g * HH + pj] + bhh0[g * HH + pj];
        b1[g] = bih1[g * HH + pj] + bhh1[g * HH + pj];
    }

    __syncthreads();   // LDS weights ready

    const int arow = w * 16 + l15;      // this lane's A-row (batch row)

    #define BIDX(kc) (((size_t)((kc) * 4 + quad) * 16 + l15) * 8)

    for (int p = 0; p <= TT; ++p) {
        f32x4 acc0 = (f32x4)0.0f, acc1 = (f32x4)0.0f;

        // (a) x-part of layer 0 — static data, runs before the barrier wait
        if (p < TT) {
            const u16* ap = Xb + ((size_t)p * BB + arow) * EE + quad * 8;
            #pragma unroll 8
            for (int kc = 0; kc < 16; ++kc) {
                s8v a = *(const s8v*)(ap + kc * 32);
                s8v b = *(const s8v*)(W0x + BIDX(kc));
                acc0 = MFMA(a, b, acc0);
            }
        }

        // (b) wait for previous phase's writers (no cache invalidation:
        //     ring addresses below were never locally cached)
        if (p > 0) {
            if (tid == 0) {
                const int target = 256 * p;
                while (__hip_atomic_load(barcnt, __ATOMIC_RELAXED,
                                         __HIP_MEMORY_SCOPE_AGENT) < target) {
                    __builtin_amdgcn_s_sleep(2);
                }
            }
            __syncthreads();
            asm volatile("" ::: "memory");   // compiler-only fence
        }

        // (c) h-dependent GEMMs — FUSED: both ring streams in one loop so the
        //     two cold-miss streams interleave (2 global A-loads + 3 MFMAs/iter)
        const u16* h0p = h0ring + (size_t)p * BH;   // h0^{(p)}
        const u16* a0p = h0p + (size_t)arow * HH + quad * 8;
        if (p == 0) {
            #pragma unroll 8
            for (int kc = 0; kc < 32; ++kc) {
                s8v a = *(const s8v*)(a0p + kc * 32);
                acc0 = MFMA(a, *(const s8v*)(W0h + BIDX(kc)), acc0);
            }
        } else {
            const u16* h1p = (p == 1) ? h1init : (H1all + (size_t)(p - 2) * BH);
            const u16* a1p = h1p + (size_t)arow * HH + quad * 8;
            if (p < TT) {
                #pragma unroll 8
                for (int kc = 0; kc < 32; ++kc) {
                    s8v a0 = *(const s8v*)(a0p + kc * 32);
                    s8v a1 = *(const s8v*)(a1p + kc * 32);
                    acc0 = MFMA(a0, *(const s8v*)(W0h + BIDX(kc)), acc0);
                    acc1 = MFMA(a0, *(const s8v*)(W1x + BIDX(kc)), acc1);
                    acc1 = MFMA(a1, *(const s8v*)(W1h + BIDX(kc)), acc1);
                }
            } else {   // p == TT: layer-1 only
                #pragma unroll 8
                for (int kc = 0; kc < 32; ++kc) {
                    s8v a0 = *(const s8v*)(a0p + kc * 32);
                    s8v a1 = *(const s8v*)(a1p + kc * 32);
                    acc1 = MFMA(a0, *(const s8v*)(W1x + BIDX(kc)), acc1);
                    acc1 = MFMA(a1, *(const s8v*)(W1h + BIDX(kc)), acc1);
                }
            }
        }

        // (d) pointwise — merged: stage both gate tiles, ONE barrier pair
        if (p < TT) {
            #pragma unroll
            for (int r = 0; r < 4; ++r)
                gst0[w * 320 + (quad * 4 + r) * 20 + l15] = acc0[r];
        }
        if (p > 0) {
            #pragma unroll
            for (int r = 0; r < 4; ++r)
                gst1[w * 320 + (quad * 4 + r) * 20 + l15] = acc1[r];
        }
        __syncthreads();
        if (p < TT) {   // layer 0 (writes h0ring slot p+1)
            const float* gr = gst0 + pw * 320 + pr16 * 20;
            const float gi = gr[0 + pjj]  + b0[0];
            const float gf = gr[4 + pjj]  + b0[1];
            const float gg = gr[8 + pjj]  + b0[2];
            const float go = gr[12 + pjj] + b0[3];
            c0 = sigm(gf) * c0 + sigm(gi) * tanh_(gg);
            const float h = sigm(go) * tanh_(c0);
            h0ring[(size_t)(p + 1) * BH + (size_t)prow * HH + pj] = f2b(h);
            if (p == TT - 1) {
                outT[(size_t)0 * BH + (size_t)prow * HH + pj] = h;    // hT layer0
                outT[(size_t)2 * BH + (size_t)prow * HH + pj] = c0;   // cT layer0
            }
        }
        if (p > 0) {    // layer 1 (writes H1all slot p-1)
            const float* gr = gst1 + pw * 320 + pr16 * 20;
            const float gi = gr[0 + pjj]  + b1[0];
            const float gf = gr[4 + pjj]  + b1[1];
            const float gg = gr[8 + pjj]  + b1[2];
            const float go = gr[12 + pjj] + b1[3];
            c1 = sigm(gf) * c1 + sigm(gi) * tanh_(gg);
            const float h = sigm(go) * tanh_(c1);
            H1all[(size_t)(p - 1) * BH + (size_t)prow * HH + pj] = f2b(h);
            if (p == TT) {
                outT[(size_t)1 * BH + (size_t)prow * HH + pj] = h;    // hT layer1
                outT[(size_t)3 * BH + (size_t)prow * HH + pj] = c1;   // cT layer1
            }
        }
        __syncthreads();   // all h stores drained (vmcnt) before the release

        // (e) arrive: RELEASE = vmcnt drain + XCD-L2 writeback, then add
        if (p < TT && tid == 0) {
            __hip_atomic_fetch_add(barcnt, 1, __ATOMIC_RELEASE,
                                   __HIP_MEMORY_SCOPE_AGENT);
        }
    }
    #undef BIDX
}

// ---------------------------------------------------------------------------
// C[M,N] = act(A1 @ W[:, :K1]^T + A2 @ W[:, K1:]^T + bias)
// A/W bf16, bias fp32. Out: bf16 (Cb) or fp32 (Cf). Tile 64x64, 4 waves.
// ---------------------------------------------------------------------------
__global__ __launch_bounds__(256)
void gemm_bt_k(const u16* __restrict__ A1, int K1,
               const u16* __restrict__ A2, int K2,
               const u16* __restrict__ W, int ldw,
               const float* __restrict__ bias,
               u16* __restrict__ Cb, float* __restrict__ Cf,
               int N, int act)
{
    const int lane = threadIdx.x & 63;
    const int wave = threadIdx.x >> 6;
    const int l15 = lane & 15, quad = lane >> 4;
    const int n0 = blockIdx.x * 64;
    const int mrow = blockIdx.y * 64 + wave * 16;
    const int arow = mrow + l15;

    f32x4 acc[4];
    #pragma unroll
    for (int nt = 0; nt < 4; ++nt) acc[nt] = (f32x4)0.0f;

    const u16* wr0 = W + (size_t)(n0 + 0 * 16 + l15) * ldw + quad * 8;
    const u16* wr1 = W + (size_t)(n0 + 1 * 16 + l15) * ldw + quad * 8;
    const u16* wr2 = W + (size_t)(n0 + 2 * 16 + l15) * ldw + quad * 8;
    const u16* wr3 = W + (size_t)(n0 + 3 * 16 + l15) * ldw + quad * 8;

    {
        const u16* ap = A1 + (size_t)arow * K1 + quad * 8;
        #pragma unroll 4
        for (int kk = 0; kk < K1; kk += 32) {
            s8v a = *(const s8v*)(ap + kk);
            acc[0] = MFMA(a, *(const s8v*)(wr0 + kk), acc[0]);
            acc[1] = MFMA(a, *(const s8v*)(wr1 + kk), acc[1]);
            acc[2] = MFMA(a, *(const s8v*)(wr2 + kk), acc[2]);
            acc[3] = MFMA(a, *(const s8v*)(wr3 + kk), acc[3]);
        }
    }
    if (A2 != nullptr) {
        const u16* ap = A2 + (size_t)arow * K2 + quad * 8;
        #pragma unroll 4
        for (int kk = 0; kk < K2; kk += 32) {
            s8v a = *(const s8v*)(ap + kk);
            acc[0] = MFMA(a, *(const s8v*)(wr0 + K1 + kk), acc[0]);
            acc[1] = MFMA(a, *(const s8v*)(wr1 + K1 + kk), acc[1]);
            acc[2] = MFMA(a, *(const s8v*)(wr2 + K1 + kk), acc[2]);
            acc[3] = MFMA(a, *(const s8v*)(wr3 + K1 + kk), acc[3]);
        }
    }
    #pragma unroll
    for (int nt = 0; nt < 4; ++nt) {
        const int col = n0 + nt * 16 + l15;
        const float bv = bias[col];
        #pragma unroll
        for (int r = 0; r < 4; ++r) {
            const int row = mrow + quad * 4 + r;
            float v = acc[nt][r] + bv;
            if (act) v = tanh_(v);
            if (Cf) Cf[(size_t)row * N + col] = v;
            else    Cb[(size_t)row * N + col] = f2b(v);
        }
    }
}

// ---------------------------------------------------------------------------
// Attention: per block (b, 16-t chunk): scores = gamma @ ctx^T (MFMA, ctx
// cast on the fly), softmax over S in LDS, ct = w @ ctx (fp32 vector).
// ---------------------------------------------------------------------------
__global__ __launch_bounds__(256)
void attn_k(const u16* __restrict__ gamma, const float* __restrict__ ctx,
            u16* __restrict__ ctall)
{
    const int b = blockIdx.x;
    const int t0 = blockIdx.y * 16;
    const int tid = threadIdx.x;
    const int lane = tid & 63, wave = tid >> 6;
    const int l15 = lane & 15, quad = lane >> 4;

    __shared__ float sw[16 * SS];

    {
        f32x4 acc0 = (f32x4)0.0f, acc1 = (f32x4)0.0f;
        const u16*   ap  = gamma + ((size_t)(t0 + l15) * BB + b) * HH + quad * 8;
        const float* bp0 = ctx + ((size_t)b * SS + (wave * 32 + l15)) * HH + quad * 8;
        const float* bp1 = ctx + ((size_t)b * SS + (wave * 32 + 16 + l15)) * HH + quad * 8;
        for (int kk = 0; kk < HH; kk += 32) {
            s8v a = *(const s8v*)(ap + kk);
            float4 u0 = *(const float4*)(bp0 + kk);
            float4 u1 = *(const float4*)(bp0 + kk + 4);
            s8v bv;
            bv[0] = (short)f2b(u0.x); bv[1] = (short)f2b(u0.y);
            bv[2] = (short)f2b(u0.z); bv[3] = (short)f2b(u0.w);
            bv[4] = (short)f2b(u1.x); bv[5] = (short)f2b(u1.y);
            bv[6] = (short)f2b(u1.z); bv[7] = (short)f2b(u1.w);
            acc0 = MFMA(a, bv, acc0);
            float4 w0 = *(const float4*)(bp1 + kk);
            float4 w1 = *(const float4*)(bp1 + kk + 4);
            s8v cv;
            cv[0] = (short)f2b(w0.x); cv[1] = (short)f2b(w0.y);
            cv[2] = (short)f2b(w0.z); cv[3] = (short)f2b(w0.w);
            cv[4] = (short)f2b(w1.x); cv[5] = (short)f2b(w1.y);
            cv[6] = (short)f2b(w1.z); cv[7] = (short)f2b(w1.w);
            acc1 = MFMA(a, cv, acc1);
        }
        #pragma unroll
        for (int r = 0; r < 4; ++r) {
            const int trow = quad * 4 + r;
            sw[trow * SS + wave * 32 + l15] = acc0[r];
            sw[trow * SS + wave * 32 + 16 + l15] = acc1[r];
        }
    }
    __syncthreads();

    {
        const int row = tid >> 4, c0 = tid & 15;
        float e[8];
        float m = -1e30f;
        #pragma unroll
        for (int k = 0; k < 8; ++k) { e[k] = sw[row * SS + c0 + k * 16]; m = fmaxf(m, e[k]); }
        #pragma unroll
        for (int off = 8; off >= 1; off >>= 1) m = fmaxf(m, __shfl_xor(m, off));
        float s = 0.0f;
        #pragma unroll
        for (int k = 0; k < 8; ++k) { e[k] = __expf(e[k] - m); s += e[k]; }
        #pragma unroll
        for (int off = 8; off >= 1; off >>= 1) s += __shfl_xor(s, off);
        const float inv = 1.0f / s;
        #pragma unroll
        for (int k = 0; k < 8; ++k) sw[row * SS + c0 + k * 16] = e[k] * inv;
    }
    __syncthreads();

    {
        const int h0 = tid * 4;
        float a[16][4];
        #pragma unroll
        for (int t = 0; t < 16; ++t)
            #pragma unroll
            for (int q = 0; q < 4; ++q) a[t][q] = 0.0f;

        const float* cp = ctx + (size_t)b * SS * HH + h0;
        for (int s = 0; s < SS; ++s) {
            const float4 cv = *(const float4*)(cp + (size_t)s * HH);
            #pragma unroll
            for (int t = 0; t < 16; ++t) {
                const float wgt = sw[t * SS + s];
                a[t][0] += wgt * cv.x;
                a[t][1] += wgt * cv.y;
                a[t][2] += wgt * cv.z;
                a[t][3] += wgt * cv.w;
            }
        }
        #pragma unroll
        for (int t = 0; t < 16; ++t) {
            u16* op = ctall + ((size_t)(t0 + t) * BB + b) * HH + h0;
            #pragma unroll
            for (int q = 0; q < 4; ++q) op[q] = f2b(a[t][q]);
        }
    }
}

// ---------------------------------------------------------------------------
extern "C" void kernel_launch(void* const* d_in, const int* in_sizes, int n_in,
                              void* d_out, int out_size, void* d_ws, size_t ws_size,
                              hipStream_t stream)
{
    const int*   toks = (const int*)d_in[0];
    const float* h0in = (const float*)d_in[1];
    const float* c0in = (const float*)d_in[2];
    const float* ctx  = (const float*)d_in[3];
    const float* emb  = (const float*)d_in[4];
    const float* Wih0 = (const float*)d_in[5];
    const float* Whh0 = (const float*)d_in[6];
    const float* bih0 = (const float*)d_in[7];
    const float* bhh0 = (const float*)d_in[8];
    const float* Wih1 = (const float*)d_in[9];
    const float* Whh1 = (const float*)d_in[10];
    const float* bih1 = (const float*)d_in[11];
    const float* bhh1 = (const float*)d_in[12];
    const float* attW = (const float*)d_in[13];
    const float* attb = (const float*)d_in[14];
    const float* outW = (const float*)d_in[15];
    const float* outb = (const float*)d_in[16];

    // workspace layout (~125 MB)
    u16*   h0ring = (u16*)d_ws;                          // 129*BH (write-once ring)
    u16*   h1init = h0ring + (size_t)(TT + 1) * BH;      // BH
    int*   barcnt = (int*)(h1init + BH);                 // 1 int (pad 64)
    u16*   Xb     = (u16*)(barcnt + 64);                 // T*B*E
    u16*   H1all  = Xb + (size_t)TT * BB * EE;           // T*BH (h1 ring + tail input)
    u16*   gammaA = H1all + (size_t)TT * BH;             // T*BH
    u16*   attWb  = gammaA + (size_t)TT * BH;            // H*H
    u16*   outWb  = attWb + (size_t)HH * HH;             // H*2H
    u16*   ctall  = h0ring;   // alias: scan is done before attn_k writes here

    // one-time conversions for the batched tail
    cvt_k<<<dim3((HH * HH / 4 + 255) / 256), 256, 0, stream>>>(attW, attWb, HH * HH);
    cvt_k<<<dim3((2 * HH * HH / 4 + 255) / 256), 256, 0, stream>>>(outW, outWb, 2 * HH * HH);

    gather_k<<<dim3(TT * BB), 128, 0, stream>>>(toks, emb, Xb);
    init_k<<<dim3(2 * BH / 256), 256, 0, stream>>>(h0in, h0ring, h1init, barcnt);

    // persistent fused LSTM scan (writes H1all + hT/cT tail of d_out)
    float* outp = (float*)d_out;
    const int ldsBytes = (16*4*16*8 + 3 * 32*4*16*8) * 2 + 2 * 8*16*20 * 4;  // 135168
    hipFuncSetAttribute((const void*)scan_k,
                        hipFuncAttributeMaxDynamicSharedMemorySize, ldsBytes);
    scan_k<<<dim3(256), 512, ldsBytes, stream>>>(
        Wih0, Whh0, Wih1, Whh1, bih0, bhh0, bih1, bhh1, c0in,
        Xb, h0ring, h1init, H1all, outp + (size_t)TT * BH, barcnt);

    // gamma = H1all @ attW^T + attb  (bf16 out)
    gemm_bt_k<<<dim3(HH / 64, (TT * BB) / 64), 256, 0, stream>>>(
        H1all, HH, nullptr, 0, attWb, HH, attb, gammaA, nullptr, HH, 0);

    // scores -> softmax -> ct
    attn_k<<<dim3(BB, TT / 16), 256, 0, stream>>>(gammaA, ctx, ctall);

    // out = tanh([ct, h1] @ outW^T + outb)  (fp32 out -> d_out)
    gemm_bt_k<<<dim3(HH / 64, (TT * BB) / 64), 256, 0, stream>>>(
        ctall, HH, H1all, HH, outWb, 2 * HH, outb, nullptr, outp, HH, 1);
}

// Round 4
// 3705.848 us; speedup vs baseline: 1.1507x; 1.1507x over previous
//
#include <hip/hip_runtime.h>

// Problem constants: T=128, B=128, S=128, H=1024, E=512, V=32000, L=2
#define TT 128
#define BB 128
#define SS 128
#define HH 1024
#define EE 512
#define BH (BB*HH)   // 131072

typedef unsigned short u16;                                   // bf16 bits
typedef unsigned long long u64;
typedef __attribute__((ext_vector_type(8))) short s8v;        // MFMA A/B fragment (8 bf16)
typedef __attribute__((ext_vector_type(4))) float f32x4;      // MFMA C/D fragment

__device__ __forceinline__ float b2f(u16 u) {
    union { unsigned int i; float f; } v; v.i = ((unsigned int)u) << 16; return v.f;
}
__device__ __forceinline__ u16 f2b(float f) {
    union { float f; unsigned int i; } v; v.f = f;
    unsigned int x = v.i;
    x = x + 0x7fffu + ((x >> 16) & 1u);   // round-to-nearest-even
    return (u16)(x >> 16);
}
__device__ __forceinline__ float sigm(float x) {
    float t = __expf(-fabsf(x));
    float p = 1.0f / (1.0f + t);
    return x >= 0.0f ? p : 1.0f - p;
}
__device__ __forceinline__ float tanh_(float x) {
    float t = __expf(-2.0f * fabsf(x));
    float r = (1.0f - t) / (1.0f + t);
    return x >= 0.0f ? r : -r;
}

#define MFMA(a, b, c) __builtin_amdgcn_mfma_f32_16x16x32_bf16((a), (b), (c), 0, 0, 0)

// ---------------------------------------------------------------------------
// fp32 -> bf16 bulk convert (n multiple of 4)
// ---------------------------------------------------------------------------
__global__ __launch_bounds__(256)
void cvt_k(const float* __restrict__ s, u16* __restrict__ d, int n)
{
    const int i = (blockIdx.x * 256 + threadIdx.x) * 4;
    if (i < n) {
        const float4 v = *(const float4*)(s + i);
        ushort4 o;
        o.x = f2b(v.x); o.y = f2b(v.y); o.z = f2b(v.z); o.w = f2b(v.w);
        *(ushort4*)(d + i) = o;
    }
}

// ---------------------------------------------------------------------------
// Embedding gather + cast: X[t*B+b, :] = bf16(emb[toks[t,b], :])
// ---------------------------------------------------------------------------
__global__ __launch_bounds__(128)
void gather_k(const int* __restrict__ toks, const float* __restrict__ emb,
              u16* __restrict__ X)
{
    const int row = blockIdx.x;
    const int tok = toks[row];
    const int c = threadIdx.x * 4;
    const float4 v = *(const float4*)(emb + (size_t)tok * EE + c);
    ushort4 o;
    o.x = f2b(v.x); o.y = f2b(v.y); o.z = f2b(v.z); o.w = f2b(v.w);
    *(ushort4*)(X + (size_t)row * EE + c) = o;
}

// ---------------------------------------------------------------------------
// init: h0ring slot0 <- bf16(h0 layer0); h1init <- bf16(h0 layer1); barcnt=0
// ---------------------------------------------------------------------------
__global__ __launch_bounds__(256)
void init_k(const float* __restrict__ h0in,
            u16* __restrict__ h0ring, u16* __restrict__ h1init,
            int* __restrict__ barcnt)
{
    const int i = blockIdx.x * 256 + threadIdx.x;   // [0, 2*BH)
    const u16 hb = f2b(h0in[i]);
    if (i < BH) h0ring[i] = hb;
    else        h1init[i - BH] = hb;
    if (i < 256) barcnt[i] = 0;   // 8 group counters (32 ints / 128 B apart)
}

// ---------------------------------------------------------------------------
// Persistent fused 2-layer LSTM scan. 256 blocks (1/CU) x 512 threads.
// Weights LDS-resident. h-state flows through WRITE-ONCE ring buffers.
//
// R2 sync redesign (theory: agent-RELEASE's buffer_wbl2 L2-walk per block per
// phase + 256-way RMW contention was ~70% of phase time):
//   * h stores are packed 8B AGENT-scope RELAXED ATOMIC stores -> write-through
//     to LLC (no dirty L2 lines, remote XCDs read fresh data from LLC).
//   * arrival RMW is RELAXED (no wbl2). Ordering: the __syncthreads() before
//     it drains each wave's vmcnt; write-through stores ack from the
//     coherence point, so all h values are LLC-visible before the RMW.
//   * 8 arrival counters (one per 32-block group, 128B apart) cut RMW
//     contention 256-way -> 32-way; tids 0..7 poll them in parallel.
//   * pointwise: threads 0..127 do layer-0 rows, threads 128..255 layer-1
//     rows CONCURRENTLY (4 cols each -> one packed 8B store per row).
// Readers use plain cached loads with NO cache invalidation: a ring address
// was never locally cached (write-once ring), so the first read per XCD
// misses to LLC, which is fresh per the above.
// ---------------------------------------------------------------------------
__global__ __launch_bounds__(512, 1)
void scan_k(const float* __restrict__ Wih0, const float* __restrict__ Whh0,
            const float* __restrict__ Wih1, const float* __restrict__ Whh1,
            const float* __restrict__ bih0, const float* __restrict__ bhh0,
            const float* __restrict__ bih1, const float* __restrict__ bhh1,
            const float* __restrict__ c0in,
            const u16* __restrict__ Xb,
            u16* __restrict__ h0ring,   // 129 slots of BH (slot 0 = init)
            const u16* __restrict__ h1init,
            u16* __restrict__ H1all,    // T * BH (= h1 ring, slot t = step t)
            float* __restrict__ outT,   // d_out + T*BH: [hT (2BH), cT (2BH)]
            int* __restrict__ barcnt)   // 8 counters at stride 32 ints
{
    extern __shared__ u16 lds[];
    u16* W0x = lds;                     // 16*4*16*8  =  8192 u16 (16 KB)
    u16* W0h = W0x + 16*4*16*8;         // 32*4*16*8  = 16384 u16 (32 KB)
    u16* W1x = W0h + 32*4*16*8;         //            = 16384 u16 (32 KB)
    u16* W1h = W1x + 32*4*16*8;         //            = 16384 u16 (32 KB)
    float* gst0 = (float*)(W1h + 32*4*16*8);  // 8*16*20 = 2560 fp32 (10 KB)
    float* gst1 = gst0 + 8*16*20;             // 8*16*20 = 2560 fp32 (10 KB)

    const int tid  = threadIdx.x;
    const int bk   = blockIdx.x;
    // swizzle: XCD (bk&7) owns contiguous 128-col span
    const int j0   = (((bk & 7) << 5) | (bk >> 3)) * 4;
    const int lane = tid & 63;
    const int w    = tid >> 6;          // wave 0..7  (m-tile = w)
    const int l15  = lane & 15, quad = lane >> 4;

    // ---- one-time: weights -> LDS (fp32 -> bf16, swizzled) ----
    auto loadW = [&](const float* src, int K, u16* dst) {
        const int ntup = (K / 32) * 4 * 16;
        for (int idx = tid; idx < ntup; idx += 512) {
            const int n = idx & 15, q = (idx >> 4) & 3, kc = idx >> 6;
            const int col = ((n >> 2) * HH) + j0 + (n & 3);   // gate*H + j
            const float* sp = src + (size_t)col * K + kc * 32 + q * 8;
            const float4 v0 = *(const float4*)(sp);
            const float4 v1 = *(const float4*)(sp + 4);
            u16* dp = dst + (size_t)idx * 8;
            dp[0] = f2b(v0.x); dp[1] = f2b(v0.y); dp[2] = f2b(v0.z); dp[3] = f2b(v0.w);
            dp[4] = f2b(v1.x); dp[5] = f2b(v1.y); dp[6] = f2b(v1.z); dp[7] = f2b(v1.w);
        }
    };
    loadW(Wih0, EE, W0x);
    loadW(Whh0, HH, W0h);
    loadW(Wih1, HH, W1x);
    loadW(Whh1, HH, W1h);

    // pointwise mapping: tid<128 -> layer0 row tid; 128<=tid<256 -> layer1
    // row tid-128. Each owns 4 output cols j0..j0+3 (c-state + bias in regs).
    const int pr = tid & 127;
    f32x4 cst = (f32x4)0.0f;
    f32x4 bs0 = (f32x4)0.0f, bs1 = (f32x4)0.0f, bs2 = (f32x4)0.0f, bs3 = (f32x4)0.0f;
    if (tid < 256) {
        const int layer = tid >> 7;
        const float* bi = layer ? bih1 : bih0;
        const float* bh = layer ? bhh1 : bhh0;
        cst = *(const f32x4*)(c0in + (size_t)layer * BH + (size_t)pr * HH + j0);
        bs0 = *(const f32x4*)(bi + 0 * HH + j0) + *(const f32x4*)(bh + 0 * HH + j0);
        bs1 = *(const f32x4*)(bi + 1 * HH + j0) + *(const f32x4*)(bh + 1 * HH + j0);
        bs2 = *(const f32x4*)(bi + 2 * HH + j0) + *(const f32x4*)(bh + 2 * HH + j0);
        bs3 = *(const f32x4*)(bi + 3 * HH + j0) + *(const f32x4*)(bh + 3 * HH + j0);
    }

    __syncthreads();   // LDS weights ready

    const int arow = w * 16 + l15;      // this lane's A-row (batch row)

    #define BIDX(kc) (((size_t)((kc) * 4 + quad) * 16 + l15) * 8)

    // pointwise worker: gates from gbase row pr, update cst, store packed h
    auto pointwise = [&](const float* gbase, u16* dst, float* oH, float* oC,
                         bool doOut) {
        const float* gr = gbase + (pr >> 4) * 320 + (pr & 15) * 20;
        const f32x4 vi = *(const f32x4*)(gr + 0);
        const f32x4 vf = *(const f32x4*)(gr + 4);
        const f32x4 vg = *(const f32x4*)(gr + 8);
        const f32x4 vo = *(const f32x4*)(gr + 12);
        f32x4 hv;
        #pragma unroll
        for (int jj = 0; jj < 4; ++jj) {
            const float gi = vi[jj] + bs0[jj];
            const float gf = vf[jj] + bs1[jj];
            const float gg = vg[jj] + bs2[jj];
            const float go = vo[jj] + bs3[jj];
            const float c = sigm(gf) * cst[jj] + sigm(gi) * tanh_(gg);
            cst[jj] = c;
            hv[jj] = sigm(go) * tanh_(c);
        }
        const u64 pk = (u64)f2b(hv[0]) | ((u64)f2b(hv[1]) << 16)
                     | ((u64)f2b(hv[2]) << 32) | ((u64)f2b(hv[3]) << 48);
        // write-through to LLC: no dirty L2 line, remote XCDs read fresh
        __hip_atomic_store((u64*)(dst + (size_t)pr * HH + j0), pk,
                           __ATOMIC_RELAXED, __HIP_MEMORY_SCOPE_AGENT);
        if (doOut) {
            *(f32x4*)(oH + (size_t)pr * HH + j0) = hv;
            *(f32x4*)(oC + (size_t)pr * HH + j0) = cst;
        }
    };

    for (int p = 0; p <= TT; ++p) {
        f32x4 acc0 = (f32x4)0.0f, acc1 = (f32x4)0.0f;

        // (a) x-part of layer 0 — static data, runs before the barrier wait
        if (p < TT) {
            const u16* ap = Xb + ((size_t)p * BB + arow) * EE + quad * 8;
            #pragma unroll 8
            for (int kc = 0; kc < 16; ++kc) {
                s8v a = *(const s8v*)(ap + kc * 32);
                s8v b = *(const s8v*)(W0x + BIDX(kc));
                acc0 = MFMA(a, b, acc0);
            }
        }

        // (b) wait for previous phase's writers: 8 parallel pollers, one per
        //     32-block group counter (no cache invalidation needed: ring
        //     addresses below were never locally cached)
        if (p > 0) {
            if (tid < 8) {
                const int target = 32 * p;
                while (__hip_atomic_load(barcnt + tid * 32, __ATOMIC_RELAXED,
                                         __HIP_MEMORY_SCOPE_AGENT) < target) {
                    __builtin_amdgcn_s_sleep(1);
                }
            }
            __syncthreads();
            asm volatile("" ::: "memory");   // compiler-only fence
        }

        // (c) h-dependent GEMMs — fused: both ring streams in one loop
        const u16* h0p = h0ring + (size_t)p * BH;   // h0^{(p)}
        const u16* a0p = h0p + (size_t)arow * HH + quad * 8;
        if (p == 0) {
            #pragma unroll 8
            for (int kc = 0; kc < 32; ++kc) {
                s8v a = *(const s8v*)(a0p + kc * 32);
                acc0 = MFMA(a, *(const s8v*)(W0h + BIDX(kc)), acc0);
            }
        } else {
            const u16* h1p = (p == 1) ? h1init : (H1all + (size_t)(p - 2) * BH);
            const u16* a1p = h1p + (size_t)arow * HH + quad * 8;
            if (p < TT) {
                #pragma unroll 8
                for (int kc = 0; kc < 32; ++kc) {
                    s8v a0 = *(const s8v*)(a0p + kc * 32);
                    s8v a1 = *(const s8v*)(a1p + kc * 32);
                    acc0 = MFMA(a0, *(const s8v*)(W0h + BIDX(kc)), acc0);
                    acc1 = MFMA(a0, *(const s8v*)(W1x + BIDX(kc)), acc1);
                    acc1 = MFMA(a1, *(const s8v*)(W1h + BIDX(kc)), acc1);
                }
            } else {   // p == TT: layer-1 only
                #pragma unroll 8
                for (int kc = 0; kc < 32; ++kc) {
                    s8v a0 = *(const s8v*)(a0p + kc * 32);
                    s8v a1 = *(const s8v*)(a1p + kc * 32);
                    acc1 = MFMA(a0, *(const s8v*)(W1x + BIDX(kc)), acc1);
                    acc1 = MFMA(a1, *(const s8v*)(W1h + BIDX(kc)), acc1);
                }
            }
        }

        // (d) stage gate tiles, ONE barrier pair, concurrent L0/L1 pointwise
        if (p < TT) {
            #pragma unroll
            for (int r = 0; r < 4; ++r)
                gst0[w * 320 + (quad * 4 + r) * 20 + l15] = acc0[r];
        }
        if (p > 0) {
            #pragma unroll
            for (int r = 0; r < 4; ++r)
                gst1[w * 320 + (quad * 4 + r) * 20 + l15] = acc1[r];
        }
        __syncthreads();
        if (p < TT && tid < 128)
            pointwise(gst0, h0ring + (size_t)(p + 1) * BH,
                      outT + (size_t)0 * BH, outT + (size_t)2 * BH, p == TT - 1);
        if (p > 0 && tid >= 128 && tid < 256)
            pointwise(gst1, H1all + (size_t)(p - 1) * BH,
                      outT + (size_t)1 * BH, outT + (size_t)3 * BH, p == TT);
        __syncthreads();   // drains vmcnt per wave: h stores LLC-visible

        // (e) arrive: RELAXED agent RMW on this group's counter (no wbl2 —
        //     write-through h stores already performed at the LLC)
        if (p < TT && tid == 0) {
            __hip_atomic_fetch_add(barcnt + (bk & 7) * 32, 1, __ATOMIC_RELAXED,
                                   __HIP_MEMORY_SCOPE_AGENT);
        }
    }
    #undef BIDX
}

// ---------------------------------------------------------------------------
// C[M,N] = act(A1 @ W[:, :K1]^T + A2 @ W[:, K1:]^T + bias)
// A/W bf16, bias fp32. Out: bf16 (Cb) or fp32 (Cf). Tile 64x64, 4 waves.
// ---------------------------------------------------------------------------
__global__ __launch_bounds__(256)
void gemm_bt_k(const u16* __restrict__ A1, int K1,
               const u16* __restrict__ A2, int K2,
               const u16* __restrict__ W, int ldw,
               const float* __restrict__ bias,
               u16* __restrict__ Cb, float* __restrict__ Cf,
               int N, int act)
{
    const int lane = threadIdx.x & 63;
    const int wave = threadIdx.x >> 6;
    const int l15 = lane & 15, quad = lane >> 4;
    const int n0 = blockIdx.x * 64;
    const int mrow = blockIdx.y * 64 + wave * 16;
    const int arow = mrow + l15;

    f32x4 acc[4];
    #pragma unroll
    for (int nt = 0; nt < 4; ++nt) acc[nt] = (f32x4)0.0f;

    const u16* wr0 = W + (size_t)(n0 + 0 * 16 + l15) * ldw + quad * 8;
    const u16* wr1 = W + (size_t)(n0 + 1 * 16 + l15) * ldw + quad * 8;
    const u16* wr2 = W + (size_t)(n0 + 2 * 16 + l15) * ldw + quad * 8;
    const u16* wr3 = W + (size_t)(n0 + 3 * 16 + l15) * ldw + quad * 8;

    {
        const u16* ap = A1 + (size_t)arow * K1 + quad * 8;
        #pragma unroll 4
        for (int kk = 0; kk < K1; kk += 32) {
            s8v a = *(const s8v*)(ap + kk);
            acc[0] = MFMA(a, *(const s8v*)(wr0 + kk), acc[0]);
            acc[1] = MFMA(a, *(const s8v*)(wr1 + kk), acc[1]);
            acc[2] = MFMA(a, *(const s8v*)(wr2 + kk), acc[2]);
            acc[3] = MFMA(a, *(const s8v*)(wr3 + kk), acc[3]);
        }
    }
    if (A2 != nullptr) {
        const u16* ap = A2 + (size_t)arow * K2 + quad * 8;
        #pragma unroll 4
        for (int kk = 0; kk < K2; kk += 32) {
            s8v a = *(const s8v*)(ap + kk);
            acc[0] = MFMA(a, *(const s8v*)(wr0 + K1 + kk), acc[0]);
            acc[1] = MFMA(a, *(const s8v*)(wr1 + K1 + kk), acc[1]);
            acc[2] = MFMA(a, *(const s8v*)(wr2 + K1 + kk), acc[2]);
            acc[3] = MFMA(a, *(const s8v*)(wr3 + K1 + kk), acc[3]);
        }
    }
    #pragma unroll
    for (int nt = 0; nt < 4; ++nt) {
        const int col = n0 + nt * 16 + l15;
        const float bv = bias[col];
        #pragma unroll
        for (int r = 0; r < 4; ++r) {
            const int row = mrow + quad * 4 + r;
            float v = acc[nt][r] + bv;
            if (act) v = tanh_(v);
            if (Cf) Cf[(size_t)row * N + col] = v;
            else    Cb[(size_t)row * N + col] = f2b(v);
        }
    }
}

// ---------------------------------------------------------------------------
// Attention: per block (b, 16-t chunk): scores = gamma @ ctx^T (MFMA, ctx
// cast on the fly), softmax over S in LDS, ct = w @ ctx (fp32 vector).
// ---------------------------------------------------------------------------
__global__ __launch_bounds__(256)
void attn_k(const u16* __restrict__ gamma, const float* __restrict__ ctx,
            u16* __restrict__ ctall)
{
    const int b = blockIdx.x;
    const int t0 = blockIdx.y * 16;
    const int tid = threadIdx.x;
    const int lane = tid & 63, wave = tid >> 6;
    const int l15 = lane & 15, quad = lane >> 4;

    __shared__ float sw[16 * SS];

    {
        f32x4 acc0 = (f32x4)0.0f, acc1 = (f32x4)0.0f;
        const u16*   ap  = gamma + ((size_t)(t0 + l15) * BB + b) * HH + quad * 8;
        const float* bp0 = ctx + ((size_t)b * SS + (wave * 32 + l15)) * HH + quad * 8;
        const float* bp1 = ctx + ((size_t)b * SS + (wave * 32 + 16 + l15)) * HH + quad * 8;
        for (int kk = 0; kk < HH; kk += 32) {
            s8v a = *(const s8v*)(ap + kk);
            float4 u0 = *(const float4*)(bp0 + kk);
            float4 u1 = *(const float4*)(bp0 + kk + 4);
            s8v bv;
            bv[0] = (short)f2b(u0.x); bv[1] = (short)f2b(u0.y);
            bv[2] = (short)f2b(u0.z); bv[3] = (short)f2b(u0.w);
            bv[4] = (short)f2b(u1.x); bv[5] = (short)f2b(u1.y);
            bv[6] = (short)f2b(u1.z); bv[7] = (short)f2b(u1.w);
            acc0 = MFMA(a, bv, acc0);
            float4 w0 = *(const float4*)(bp1 + kk);
            float4 w1 = *(const float4*)(bp1 + kk + 4);
            s8v cv;
            cv[0] = (short)f2b(w0.x); cv[1] = (short)f2b(w0.y);
            cv[2] = (short)f2b(w0.z); cv[3] = (short)f2b(w0.w);
            cv[4] = (short)f2b(w1.x); cv[5] = (short)f2b(w1.y);
            cv[6] = (short)f2b(w1.z); cv[7] = (short)f2b(w1.w);
            acc1 = MFMA(a, cv, acc1);
        }
        #pragma unroll
        for (int r = 0; r < 4; ++r) {
            const int trow = quad * 4 + r;
            sw[trow * SS + wave * 32 + l15] = acc0[r];
            sw[trow * SS + wave * 32 + 16 + l15] = acc1[r];
        }
    }
    __syncthreads();

    {
        const int row = tid >> 4, c0 = tid & 15;
        float e[8];
        float m = -1e30f;
        #pragma unroll
        for (int k = 0; k < 8; ++k) { e[k] = sw[row * SS + c0 + k * 16]; m = fmaxf(m, e[k]); }
        #pragma unroll
        for (int off = 8; off >= 1; off >>= 1) m = fmaxf(m, __shfl_xor(m, off));
        float s = 0.0f;
        #pragma unroll
        for (int k = 0; k < 8; ++k) { e[k] = __expf(e[k] - m); s += e[k]; }
        #pragma unroll
        for (int off = 8; off >= 1; off >>= 1) s += __shfl_xor(s, off);
        const float inv = 1.0f / s;
        #pragma unroll
        for (int k = 0; k < 8; ++k) sw[row * SS + c0 + k * 16] = e[k] * inv;
    }
    __syncthreads();

    {
        const int h0 = tid * 4;
        float a[16][4];
        #pragma unroll
        for (int t = 0; t < 16; ++t)
            #pragma unroll
            for (int q = 0; q < 4; ++q) a[t][q] = 0.0f;

        const float* cp = ctx + (size_t)b * SS * HH + h0;
        for (int s = 0; s < SS; ++s) {
            const float4 cv = *(const float4*)(cp + (size_t)s * HH);
            #pragma unroll
            for (int t = 0; t < 16; ++t) {
                const float wgt = sw[t * SS + s];
                a[t][0] += wgt * cv.x;
                a[t][1] += wgt * cv.y;
                a[t][2] += wgt * cv.z;
                a[t][3] += wgt * cv.w;
            }
        }
        #pragma unroll
        for (int t = 0; t < 16; ++t) {
            u16* op = ctall + ((size_t)(t0 + t) * BB + b) * HH + h0;
            #pragma unroll
            for (int q = 0; q < 4; ++q) op[q] = f2b(a[t][q]);
        }
    }
}

// ---------------------------------------------------------------------------
extern "C" void kernel_launch(void* const* d_in, const int* in_sizes, int n_in,
                              void* d_out, int out_size, void* d_ws, size_t ws_size,
                              hipStream_t stream)
{
    const int*   toks = (const int*)d_in[0];
    const float* h0in = (const float*)d_in[1];
    const float* c0in = (const float*)d_in[2];
    const float* ctx  = (const float*)d_in[3];
    const float* emb  = (const float*)d_in[4];
    const float* Wih0 = (const float*)d_in[5];
    const float* Whh0 = (const float*)d_in[6];
    const float* bih0 = (const float*)d_in[7];
    const float* bhh0 = (const float*)d_in[8];
    const float* Wih1 = (const float*)d_in[9];
    const float* Whh1 = (const float*)d_in[10];
    const float* bih1 = (const float*)d_in[11];
    const float* bhh1 = (const float*)d_in[12];
    const float* attW = (const float*)d_in[13];
    const float* attb = (const float*)d_in[14];
    const float* outW = (const float*)d_in[15];
    const float* outb = (const float*)d_in[16];

    // workspace layout (~125 MB)
    u16*   h0ring = (u16*)d_ws;                          // 129*BH (write-once ring)
    u16*   h1init = h0ring + (size_t)(TT + 1) * BH;      // BH
    int*   barcnt = (int*)(h1init + BH);                 // 8 counters, 128B apart
    u16*   Xb     = (u16*)(barcnt + 256);                // T*B*E
    u16*   H1all  = Xb + (size_t)TT * BB * EE;           // T*BH (h1 ring + tail input)
    u16*   gammaA = H1all + (size_t)TT * BH;             // T*BH
    u16*   attWb  = gammaA + (size_t)TT * BH;            // H*H
    u16*   outWb  = attWb + (size_t)HH * HH;             // H*2H
    u16*   ctall  = h0ring;   // alias: scan is done before attn_k writes here

    // one-time conversions for the batched tail
    cvt_k<<<dim3((HH * HH / 4 + 255) / 256), 256, 0, stream>>>(attW, attWb, HH * HH);
    cvt_k<<<dim3((2 * HH * HH / 4 + 255) / 256), 256, 0, stream>>>(outW, outWb, 2 * HH * HH);

    gather_k<<<dim3(TT * BB), 128, 0, stream>>>(toks, emb, Xb);
    init_k<<<dim3(2 * BH / 256), 256, 0, stream>>>(h0in, h0ring, h1init, barcnt);

    // persistent fused LSTM scan (writes H1all + hT/cT tail of d_out)
    float* outp = (float*)d_out;
    const int ldsBytes = (16*4*16*8 + 3 * 32*4*16*8) * 2 + 2 * 8*16*20 * 4;  // 135168
    hipFuncSetAttribute((const void*)scan_k,
                        hipFuncAttributeMaxDynamicSharedMemorySize, ldsBytes);
    scan_k<<<dim3(256), 512, ldsBytes, stream>>>(
        Wih0, Whh0, Wih1, Whh1, bih0, bhh0, bih1, bhh1, c0in,
        Xb, h0ring, h1init, H1all, outp + (size_t)TT * BH, barcnt);

    // gamma = H1all @ attW^T + attb  (bf16 out)
    gemm_bt_k<<<dim3(HH / 64, (TT * BB) / 64), 256, 0, stream>>>(
        H1all, HH, nullptr, 0, attWb, HH, attb, gammaA, nullptr, HH, 0);

    // scores -> softmax -> ct
    attn_k<<<dim3(BB, TT / 16), 256, 0, stream>>>(gammaA, ctx, ctall);

    // out = tanh([ct, h1] @ outW^T + outb)  (fp32 out -> d_out)
    gemm_bt_k<<<dim3(HH / 64, (TT * BB) / 64), 256, 0, stream>>>(
        ctall, HH, H1all, HH, outWb, 2 * HH, outb, nullptr, outp, HH, 1);
}